// Round 1
// 280.433 us; speedup vs baseline: 1.0078x; 1.0078x over previous
//
#include <hip/hip_runtime.h>
#include <cstdint>
#include <cstddef>

#define WS 64
#define SHIFT 32
#define WTOT 8192
#define NWIN 128
#define SCALE_F 0.125f

typedef __bf16 bf16x8 __attribute__((ext_vector_type(8)));
typedef unsigned short u16x8 __attribute__((ext_vector_type(8)));
typedef unsigned short u16x4 __attribute__((ext_vector_type(4)));
typedef float f32x4 __attribute__((ext_vector_type(4)));

__device__ __forceinline__ unsigned short f2bf(float f) {
  unsigned int u = __builtin_bit_cast(unsigned int, f);
  u += 0x7FFFu + ((u >> 16) & 1u);   // round-to-nearest-even
  return (unsigned short)(u >> 16);
}
__device__ __forceinline__ float bf2f(unsigned short h) {
  unsigned int u = ((unsigned int)h) << 16;
  return __builtin_bit_cast(float, u);
}

// XOR-swizzle (u16 units) for [64][64]-u16 tiles whose rows are 128 B.
// byte ^= ((row>>1)&7)<<4  <=>  u16 idx ^= ((row>>1)&7)<<3.
// Only bits 3..5 of the column are flipped, so 8-element (16 B) granules
// stay intact: b128 reads/writes at col%8==0 and b64 writes at col%4==0
// remain contiguous. Verified bank math: every LDS access in this kernel
// (fragment b128 reads, K b128 stores, V^T b64 stores, P b16 stores) lands
// at the minimum bank-cycle count (conflict-free).
__device__ __forceinline__ int swz(int row, int col) {
  return (row * WS + col) ^ (((row >> 1) & 7) << 3);
}

// One block (256 thr = 4 waves) per 64x64 window. 4096 blocks.
// LDS = 4 * 8 KiB = 32768 B exactly -> 5 blocks/CU (160 KiB).
__global__ __launch_bounds__(256, 5) void win_attn(
    const float* __restrict__ q, const float* __restrict__ k,
    const float* __restrict__ v, const float* __restrict__ table,
    float* __restrict__ xout, float* __restrict__ attn_out) {
  __shared__ __align__(16) unsigned short s_khi[WS * WS];   // later P_hi
  __shared__ __align__(16) unsigned short s_klo[WS * WS];   // later P_lo
  __shared__ __align__(16) unsigned short s_vthi[WS * WS];  // V^T: [c][m]
  __shared__ __align__(16) unsigned short s_vtlo[WS * WS];

  const int t = threadIdx.x;
  const int b = blockIdx.x;            // window id 0..4095
  const int batch = b >> 7;
  const int win = b & (NWIN - 1);
  const int lane = t & 63;
  const int wave = t >> 6;             // 0..3 -> rows [16w,16w+16)
  const int lrow = lane & 15;
  const int quad = lane >> 4;

  // ---------- stage K -> hi/lo bf16 (vectorized b128 swizzled writes) ----------
  {
    const int lr = t >> 2;             // row 0..63
    const int lc = (t & 3) << 4;       // col base 0,16,32,48
    const int grow = (win * WS + lr + SHIFT) & (WTOT - 1);
    const float* kp = k + ((size_t)batch * WTOT + grow) * WS + lc;
#pragma unroll
    for (int s = 0; s < 2; ++s) {
      const float4 x0 = *(const float4*)(kp + 8 * s);
      const float4 x1 = *(const float4*)(kp + 8 * s + 4);
      const float a[8] = {x0.x, x0.y, x0.z, x0.w, x1.x, x1.y, x1.z, x1.w};
      u16x8 hi, lo;
#pragma unroll
      for (int e = 0; e < 8; ++e) {
        const unsigned short h = f2bf(a[e]);
        hi[e] = h;
        lo[e] = f2bf(a[e] - bf2f(h));
      }
      const int idx = swz(lr, lc + 8 * s);
      *(u16x8*)(s_khi + idx) = hi;
      *(u16x8*)(s_klo + idx) = lo;
    }
  }

  // ---------- stage V^T: 4x4 register micro-transpose, b64 swizzled writes ----------
  {
    const int m0 = (t >> 4) << 2;      // 4 source rows m0..m0+3
    const int c0 = (t & 15) << 2;      // 4 cols c0..c0+3 (lanes 0..15 cover a full row)
    float4 vr[4];
#pragma unroll
    for (int j = 0; j < 4; ++j) {
      const int grow = (win * WS + m0 + j + SHIFT) & (WTOT - 1);
      vr[j] = *(const float4*)(v + ((size_t)batch * WTOT + grow) * WS + c0);
    }
    const float vb[4][4] = {{vr[0].x, vr[0].y, vr[0].z, vr[0].w},
                            {vr[1].x, vr[1].y, vr[1].z, vr[1].w},
                            {vr[2].x, vr[2].y, vr[2].z, vr[2].w},
                            {vr[3].x, vr[3].y, vr[3].z, vr[3].w}};
#pragma unroll
    for (int e = 0; e < 4; ++e) {      // one V^T row segment per output col
      u16x4 hi, lo;
#pragma unroll
      for (int j = 0; j < 4; ++j) {
        const unsigned short h = f2bf(vb[j][e]);
        hi[j] = h;
        lo[j] = f2bf(vb[j][e] - bf2f(h));
      }
      const int idx = swz(c0 + e, m0);
      *(u16x4*)(s_vthi + idx) = hi;
      *(u16x4*)(s_vtlo + idx) = lo;
    }
  }

  // ---------- Q fragments straight global->reg (wave-private rows; no LDS) ----------
  bf16x8 qfhi[2], qflo[2];
  {
    const int grow = (win * WS + wave * 16 + lrow + SHIFT) & (WTOT - 1);
    const float* qp = q + ((size_t)batch * WTOT + grow) * WS + quad * 8;
#pragma unroll
    for (int kh = 0; kh < 2; ++kh) {
      const float4 x0 = *(const float4*)(qp + kh * 32);
      const float4 x1 = *(const float4*)(qp + kh * 32 + 4);
      const float a[8] = {x0.x, x0.y, x0.z, x0.w, x1.x, x1.y, x1.z, x1.w};
      u16x8 hi, lo;
#pragma unroll
      for (int e = 0; e < 8; ++e) {
        const unsigned short h = f2bf(a[e]);
        hi[e] = h;
        lo[e] = f2bf(a[e] - bf2f(h));
      }
      qfhi[kh] = __builtin_bit_cast(bf16x8, hi);
      qflo[kh] = __builtin_bit_cast(bf16x8, lo);
    }
  }

  // ---------- bias + shift-mask folded into registers (L1-resident table) ----------
  float biasr[4][4];
  {
    const bool masked = (win == NWIN - 1);
    const float* tb = table + (WS - 1);
#pragma unroll
    for (int reg = 0; reg < 4; ++reg) {
      const int r = wave * 16 + quad * 4 + reg;
#pragma unroll
      for (int j = 0; j < 4; ++j) {
        const int m = j * 16 + lrow;
        float bv = __ldg(tb + (r - m));
        if (masked && (((r ^ m) & 32) != 0)) bv -= 100.0f;
        biasr[reg][j] = bv;
      }
    }
  }
  __syncthreads();  // K, V^T visible

  // ---------- S = Q K^T via split-bf16 MFMA ----------
  const f32x4 z4 = {0.f, 0.f, 0.f, 0.f};
  f32x4 acc[4] = {z4, z4, z4, z4};
#pragma unroll
  for (int kh = 0; kh < 2; ++kh) {
    const int k0 = kh * 32 + quad * 8;
    const bf16x8 ahi = qfhi[kh];
    const bf16x8 alo = qflo[kh];
#pragma unroll
    for (int j = 0; j < 4; ++j) {
      const int idx = swz(j * 16 + lrow, k0);
      const bf16x8 bhi = *(const bf16x8*)(s_khi + idx);
      const bf16x8 blo = *(const bf16x8*)(s_klo + idx);
      acc[j] = __builtin_amdgcn_mfma_f32_16x16x32_bf16(ahi, bhi, acc[j], 0, 0, 0);
      acc[j] = __builtin_amdgcn_mfma_f32_16x16x32_bf16(alo, bhi, acc[j], 0, 0, 0);
      acc[j] = __builtin_amdgcn_mfma_f32_16x16x32_bf16(ahi, blo, acc[j], 0, 0, 0);
    }
  }

  // ---------- register softmax (rows split across the 16 lanes of a quad) ----------
  float p[4][4];  // [reg][j]
#pragma unroll
  for (int reg = 0; reg < 4; ++reg) {
    float val[4];
    float vmax = -1e30f;
#pragma unroll
    for (int j = 0; j < 4; ++j) {
      const float s = acc[j][reg] * SCALE_F + biasr[reg][j];
      val[j] = s;
      vmax = fmaxf(vmax, s);
    }
#pragma unroll
    for (int off = 1; off < 16; off <<= 1)
      vmax = fmaxf(vmax, __shfl_xor(vmax, off, 64));
    float sum = 0.f;
#pragma unroll
    for (int j = 0; j < 4; ++j) {
      val[j] = __expf(val[j] - vmax);
      sum += val[j];
    }
#pragma unroll
    for (int off = 1; off < 16; off <<= 1)
      sum += __shfl_xor(sum, off, 64);
    const float inv = 1.0f / sum;
#pragma unroll
    for (int j = 0; j < 4; ++j) p[reg][j] = val[j] * inv;
  }

  __syncthreads();  // every wave finished its K-fragment reads -> K buffers reusable

  // ---------- write attn, stage P (hi/lo) into the freed K buffers ----------
  {
    float* arow = attn_out + (size_t)b * (WS * WS);
#pragma unroll
    for (int reg = 0; reg < 4; ++reg) {
      const int r = wave * 16 + quad * 4 + reg;
#pragma unroll
      for (int j = 0; j < 4; ++j) {
        const int m = j * 16 + lrow;
        const float pv = p[reg][j];
        arow[r * WS + m] = pv;
        const unsigned short h = f2bf(pv);
        const int idx = swz(r, m);
        s_khi[idx] = h;
        s_klo[idx] = f2bf(pv - bf2f(h));
      }
    }
  }
  __syncthreads();  // P visible

  // ---------- X = P V via split-bf16 MFMA ----------
  f32x4 xacc[4] = {z4, z4, z4, z4};
#pragma unroll
  for (int kh = 0; kh < 2; ++kh) {
    const int k0 = kh * 32 + quad * 8;
    const int aidx = swz(wave * 16 + lrow, k0);
    const bf16x8 phi = *(const bf16x8*)(s_khi + aidx);
    const bf16x8 plo = *(const bf16x8*)(s_klo + aidx);
#pragma unroll
    for (int j = 0; j < 4; ++j) {
      const int idx = swz(j * 16 + lrow, k0);
      const bf16x8 vhi = *(const bf16x8*)(s_vthi + idx);
      const bf16x8 vlo = *(const bf16x8*)(s_vtlo + idx);
      xacc[j] = __builtin_amdgcn_mfma_f32_16x16x32_bf16(phi, vhi, xacc[j], 0, 0, 0);
      xacc[j] = __builtin_amdgcn_mfma_f32_16x16x32_bf16(plo, vhi, xacc[j], 0, 0, 0);
      xacc[j] = __builtin_amdgcn_mfma_f32_16x16x32_bf16(phi, vlo, xacc[j], 0, 0, 0);
    }
  }

  // ---------- store x with reverse cyclic shift ----------
#pragma unroll
  for (int reg = 0; reg < 4; ++reg) {
    const int r = wave * 16 + quad * 4 + reg;
    const int gr = (win * WS + r + SHIFT) & (WTOT - 1);
    float* xrow = xout + ((size_t)batch * WTOT + gr) * WS;
#pragma unroll
    for (int j = 0; j < 4; ++j) {
      xrow[j * 16 + lrow] = xacc[j][reg];
    }
  }
}

extern "C" void kernel_launch(void* const* d_in, const int* in_sizes, int n_in,
                              void* d_out, int out_size, void* d_ws, size_t ws_size,
                              hipStream_t stream) {
  (void)in_sizes; (void)n_in; (void)out_size; (void)d_ws; (void)ws_size;
  const float* q = (const float*)d_in[0];
  const float* k = (const float*)d_in[1];
  const float* v = (const float*)d_in[2];
  const float* table = (const float*)d_in[3];
  float* xout = (float*)d_out;                               // (32, 8192, 64)
  float* attn = (float*)d_out + (size_t)32 * WTOT * WS;      // (4096, 64, 64)
  win_attn<<<dim3(4096), dim3(256), 0, stream>>>(q, k, v, table, xout, attn);
}